// Round 5
// baseline (201.924 us; speedup 1.0000x reference)
//
#include <hip/hip_runtime.h>
#include <hip/hip_bf16.h>

#define KCB 512
#define DF  16
#define BATCH 64

__device__ __forceinline__ float bperm(int addr, float v) {
    return __int_as_float(__builtin_amdgcn_ds_bpermute(addr, __float_as_int(v)));
}

// ---------------------------------------------------------------------------
// One-shot weight transpose to [c][ky][kx][o] so conv inner loops read weights
// as block-uniform contiguous s_load_dwordx16 blocks.
// ---------------------------------------------------------------------------
__global__ __launch_bounds__(256) void wtrans_kernel(
    const float* __restrict__ w1, const float* __restrict__ w2,
    const float* __restrict__ w3, const float* __restrict__ w4,
    float* __restrict__ wt1, float* __restrict__ wt2,
    float* __restrict__ wt3, float* __restrict__ wt4)
{
    int i = blockIdx.x * 256 + threadIdx.x;
    if (i < 432) {                       // conv1: 3*9*16
        int o = i & 15, rest = i >> 4;
        int kx = rest % 3, ky = (rest / 3) % 3, c = rest / 9;
        wt1[i] = w1[((o * 3 + c) * 3 + ky) * 3 + kx];
        return;
    }
    i -= 432;
    if (i < 2304) {                      // conv2: 16*9*16
        int o = i & 15, rest = i >> 4;
        int kx = rest % 3, ky = (rest / 3) % 3, c = rest / 9;
        wt2[i] = w2[((o * 16 + c) * 3 + ky) * 3 + kx];
        return;
    }
    i -= 2304;
    if (i < 3456) {                      // conv3: 16*9*24
        int o = i % 24, rest = i / 24;
        int kx = rest % 3, ky = (rest / 3) % 3, c = rest / 9;
        wt3[i] = w3[((o * 16 + c) * 3 + ky) * 3 + kx];
        return;
    }
    i -= 3456;
    if (i < 3456) {                      // conv4: 24*9*16
        int o = i & 15, rest = i >> 4;
        int kx = rest % 3, ky = (rest / 3) % 3, c = rest / 9;
        wt4[i] = w4[((o * 24 + c) * 3 + ky) * 3 + kx];
    }
}

// ---------------------------------------------------------------------------
// conv1 (3->16, 64x64): one wave per output row. Lane = x. Per (c,ky): one
// coalesced load + 2 bpermute lane-shifts; weights via uniform s_load.
// Grid (16, B), block 256 = 4 waves = 4 rows.
// ---------------------------------------------------------------------------
__global__ __launch_bounds__(256) void conv1_row_kernel(
    const float* __restrict__ in, const float* __restrict__ wt,
    const float* __restrict__ bias, float* __restrict__ out)
{
    const int CIN = 3, COUT = 16, H = 64, W = 64;
    const int lane = threadIdx.x & 63;
    const int wv = threadIdx.x >> 6;
    const int y = blockIdx.x * 4 + wv;
    const int b = blockIdx.y;
    const int x = lane;
    const int aL = ((lane + 63) & 63) << 2;
    const int aR = ((lane + 1) & 63) << 2;

    float acc[16];
#pragma unroll
    for (int o = 0; o < 16; ++o) acc[o] = bias[o];

#pragma unroll
    for (int c = 0; c < CIN; ++c) {
#pragma unroll
        for (int ky = 0; ky < 3; ++ky) {
            int ry = y + ky - 1;
            float v = 0.f;
            if (ry >= 0 && ry < H)
                v = in[((b * CIN + c) * H + ry) * W + x];
            float vL = (x == 0)     ? 0.f : bperm(aL, v);
            float vR = (x == W - 1) ? 0.f : bperm(aR, v);
            const float* wp = wt + ((c * 3 + ky) * 3) * 16;
#pragma unroll
            for (int o = 0; o < 16; ++o) acc[o] = fmaf(vL, wp[o], acc[o]);
#pragma unroll
            for (int o = 0; o < 16; ++o) acc[o] = fmaf(v, wp[16 + o], acc[o]);
#pragma unroll
            for (int o = 0; o < 16; ++o) acc[o] = fmaf(vR, wp[32 + o], acc[o]);
        }
    }
#pragma unroll
    for (int o = 0; o < 16; ++o)
        out[((b * COUT + o) * H + y) * W + x] = fmaxf(acc[o], 0.f);
}

// ---------------------------------------------------------------------------
// conv2 (16->16, 64x64) fused with 2x2 maxpool. One wave per ROW PAIR
// (y0=2r, y0+1): per c loads 4 rows, computes both rows' 16 couts, then
// relu+pool via one bpermute. Grid (8, B), block 256 = 4 waves.
// ---------------------------------------------------------------------------
__global__ __launch_bounds__(256) void conv2_pool_kernel(
    const float* __restrict__ in, const float* __restrict__ wt,
    const float* __restrict__ bias, float* __restrict__ out)
{
    const int CIN = 16, COUT = 16, H = 64, W = 64;
    const int lane = threadIdx.x & 63;
    const int wv = threadIdx.x >> 6;
    const int r = blockIdx.x * 4 + wv;   // row pair 0..31
    const int y0 = r * 2;
    const int b = blockIdx.y;
    const int x = lane;
    const int aL = ((lane + 63) & 63) << 2;
    const int aR = ((lane + 1) & 63) << 2;

    float acc0[16], acc1[16];
#pragma unroll
    for (int o = 0; o < 16; ++o) { acc0[o] = bias[o]; acc1[o] = bias[o]; }

#pragma unroll 4
    for (int c = 0; c < CIN; ++c) {
        const float* ip = in + ((size_t)(b * CIN + c) * H) * W + x;
        float v[4], vl[4], vr[4];
#pragma unroll
        for (int j = 0; j < 4; ++j) {
            int ry = y0 - 1 + j;
            float t = 0.f;
            if (ry >= 0 && ry < H) t = ip[ry * W];
            v[j] = t;
            vl[j] = (x == 0)     ? 0.f : bperm(aL, t);
            vr[j] = (x == W - 1) ? 0.f : bperm(aR, t);
        }
#pragma unroll
        for (int ky = 0; ky < 3; ++ky) {
            const float* wp = wt + ((c * 3 + ky) * 3) * 16;
#pragma unroll
            for (int kx = 0; kx < 3; ++kx) {
                float a0 = (kx == 0) ? vl[ky]     : (kx == 1) ? v[ky]     : vr[ky];
                float a1 = (kx == 0) ? vl[ky + 1] : (kx == 1) ? v[ky + 1] : vr[ky + 1];
                const float* wq = wp + kx * 16;
#pragma unroll
                for (int o = 0; o < 16; ++o) {
                    float w = wq[o];
                    acc0[o] = fmaf(a0, w, acc0[o]);
                    acc1[o] = fmaf(a1, w, acc1[o]);
                }
            }
        }
    }

    // relu + 2x2 maxpool -> (b, o, r, x/2)
    const int px = x >> 1;
#pragma unroll
    for (int o = 0; o < 16; ++o) {
        float m = fmaxf(fmaxf(acc0[o], acc1[o]), 0.f);
        float mR = bperm(aR, m);
        m = fmaxf(m, mR);
        if ((x & 1) == 0)
            out[((b * COUT + o) * 32 + r) * 32 + px] = m;
    }
}

// ---------------------------------------------------------------------------
// conv3 (16->24, 32x32): one wave = two 32-px rows (lane = h*32 + x).
// COUT split into 4 groups of 6. Grid (4, 4, B), block 256 = 4 waves.
// ---------------------------------------------------------------------------
template<int CIN, int COUT_T, int COUT_TOTAL>
__global__ __launch_bounds__(256) void conv_rp32_kernel(
    const float* __restrict__ in, const float* __restrict__ wt,
    const float* __restrict__ bias, float* __restrict__ out)
{
    const int H = 32, W = 32;
    const int lane = threadIdx.x & 63;
    const int wv = threadIdx.x >> 6;
    const int p = blockIdx.x * 4 + wv;    // row-pair 0..15
    const int g = blockIdx.y;
    const int og = g * COUT_T;
    const int b = blockIdx.z;
    const int h = lane >> 5;
    const int x = lane & 31;
    const int y = p * 2 + h;
    const int aL = ((lane + 63) & 63) << 2;
    const int aR = ((lane + 1) & 63) << 2;

    float acc[COUT_T];
#pragma unroll
    for (int o = 0; o < COUT_T; ++o) acc[o] = bias[og + o];

#pragma unroll 4
    for (int c = 0; c < CIN; ++c) {
        const float* ip = in + ((size_t)(b * CIN + c) * H) * W;
        float v[3], vl[3], vr[3];
#pragma unroll
        for (int d = 0; d < 3; ++d) {
            int ry = y + d - 1;
            int ryc = min(max(ry, 0), H - 1);
            float t = ip[ryc * W + x];
            t = (ry == ryc) ? t : 0.f;
            v[d] = t;
            vl[d] = (x == 0)     ? 0.f : bperm(aL, t);
            vr[d] = (x == W - 1) ? 0.f : bperm(aR, t);
        }
#pragma unroll
        for (int ky = 0; ky < 3; ++ky) {
#pragma unroll
            for (int kx = 0; kx < 3; ++kx) {
                float a = (kx == 0) ? vl[ky] : (kx == 1) ? v[ky] : vr[ky];
                const float* wq = wt + ((c * 3 + ky) * 3 + kx) * COUT_TOTAL + og;
#pragma unroll
                for (int o = 0; o < COUT_T; ++o)
                    acc[o] = fmaf(a, wq[o], acc[o]);
            }
        }
    }
#pragma unroll
    for (int o = 0; o < COUT_T; ++o)
        out[((b * COUT_TOTAL + og + o) * H + y) * W + x] = fmaxf(acc[o], 0.f);
}

// ---------------------------------------------------------------------------
// conv4 (24->16, 32x32): same row-pair structure, COUT split 4x4. Writes the
// float4 slice of transposed features ft (B,1024,16) + partial sq-norm f2p.
// Grid (4, 4, B), block 256.
// ---------------------------------------------------------------------------
__global__ __launch_bounds__(256) void conv4_ft_kernel(
    const float* __restrict__ in, const float* __restrict__ wt,
    const float* __restrict__ bias, float* __restrict__ ft,
    float* __restrict__ f2p)
{
    const int CIN = 24, COUT_T = 4, H = 32, W = 32;
    const int lane = threadIdx.x & 63;
    const int wv = threadIdx.x >> 6;
    const int p = blockIdx.x * 4 + wv;
    const int g = blockIdx.y;
    const int og = g * COUT_T;
    const int b = blockIdx.z;
    const int h = lane >> 5;
    const int x = lane & 31;
    const int y = p * 2 + h;
    const int aL = ((lane + 63) & 63) << 2;
    const int aR = ((lane + 1) & 63) << 2;

    float acc[COUT_T];
#pragma unroll
    for (int o = 0; o < COUT_T; ++o) acc[o] = bias[og + o];

#pragma unroll 4
    for (int c = 0; c < CIN; ++c) {
        const float* ip = in + ((size_t)(b * CIN + c) * H) * W;
        float v[3], vl[3], vr[3];
#pragma unroll
        for (int d = 0; d < 3; ++d) {
            int ry = y + d - 1;
            int ryc = min(max(ry, 0), H - 1);
            float t = ip[ryc * W + x];
            t = (ry == ryc) ? t : 0.f;
            v[d] = t;
            vl[d] = (x == 0)     ? 0.f : bperm(aL, t);
            vr[d] = (x == W - 1) ? 0.f : bperm(aR, t);
        }
#pragma unroll
        for (int ky = 0; ky < 3; ++ky) {
#pragma unroll
            for (int kx = 0; kx < 3; ++kx) {
                float a = (kx == 0) ? vl[ky] : (kx == 1) ? v[ky] : vr[ky];
                const float* wq = wt + ((c * 3 + ky) * 3 + kx) * 16 + og;
#pragma unroll
                for (int o = 0; o < COUT_T; ++o)
                    acc[o] = fmaf(a, wq[o], acc[o]);
            }
        }
    }

    const size_t pix = (size_t)b * 1024 + y * W + x;
    float v0 = fmaxf(acc[0], 0.f), v1 = fmaxf(acc[1], 0.f);
    float v2 = fmaxf(acc[2], 0.f), v3 = fmaxf(acc[3], 0.f);
    *(float4*)(ft + pix * 16 + og) = make_float4(v0, v1, v2, v3);
    float s2 = v0 * v0;
    s2 = fmaf(v1, v1, s2);
    s2 = fmaf(v2, v2, s2);
    s2 = fmaf(v3, v3, s2);
    f2p[(size_t)g * (BATCH * 1024) + pix] = s2;
}

// ---------------------------------------------------------------------------
// BoF: dist = f2 + c2 - 2 f.c. Features read with block-uniform addresses
// (-> scalar loads). f2 partials summed once into LDS. Denominator via
// batched 512x16 LDS e-matrix column sum: 3 barriers per 16 pixels.
// Grid (8, B), block 512 (thread = codebook entry). partial: (B,8,512).
// ---------------------------------------------------------------------------
__global__ __launch_bounds__(512) void bof_kernel(
    const float* __restrict__ ft, const float* __restrict__ f2p,
    const float* __restrict__ codebook, const float* __restrict__ sigma,
    float* __restrict__ partial)
{
    const int J = 16;
    const int b = blockIdx.y;
    const int chunk = blockIdx.x;
    const int t = threadIdx.x;

    __shared__ float s_e[KCB][J + 1];
    __shared__ float s_p[32][J + 1];
    __shared__ float s_dinv[J];
    __shared__ float s_tmp[4][128];
    __shared__ float s_f2[128];

    const size_t base = (size_t)b * 1024 + chunk * 128;
    {
        const int g = t >> 7, j = t & 127;
        s_tmp[g][j] = f2p[(size_t)g * (BATCH * 1024) + base + j];
    }

    float cb[DF];
    {
        const float4* cq = (const float4*)(codebook + (size_t)t * DF);
        float4 a0 = cq[0], a1 = cq[1], a2 = cq[2], a3 = cq[3];
        cb[0]=a0.x; cb[1]=a0.y; cb[2]=a0.z; cb[3]=a0.w;
        cb[4]=a1.x; cb[5]=a1.y; cb[6]=a1.z; cb[7]=a1.w;
        cb[8]=a2.x; cb[9]=a2.y; cb[10]=a2.z; cb[11]=a2.w;
        cb[12]=a3.x; cb[13]=a3.y; cb[14]=a3.z; cb[15]=a3.w;
    }
    float c2 = 0.f;
#pragma unroll
    for (int d = 0; d < DF; ++d) c2 = fmaf(cb[d], cb[d], c2);
    const float sg = sigma[t];

    __syncthreads();
    if (t < 128) s_f2[t] = (s_tmp[0][t] + s_tmp[1][t]) + (s_tmp[2][t] + s_tmp[3][t]);
    __syncthreads();

    float acc = 0.f;

    for (int jb = 0; jb < 8; ++jb) {
        const int j0 = jb * J;
        float e[J];
#pragma unroll
        for (int jj = 0; jj < J; ++jj) {
            const float* fp = ft + (base + j0 + jj) * DF;  // uniform -> s_load
            float dot = 0.f;
#pragma unroll
            for (int d = 0; d < DF; ++d) dot = fmaf(fp[d], cb[d], dot);
            float f2c = s_f2[j0 + jj] + c2;                // LDS broadcast
            float dist = fmaf(-2.f, dot, f2c);
            e[jj] = __expf(-dist * sg);
            s_e[t][jj] = e[jj];
        }
        __syncthreads();

        {
            const int c  = t & 15;
            const int sg2 = t >> 4;
            float ps = 0.f;
#pragma unroll
            for (int r = 0; r < 16; ++r) ps += s_e[sg2 * 16 + r][c];
            s_p[sg2][c] = ps;
        }
        __syncthreads();

        if (t < J) {
            float dsum = 0.f;
#pragma unroll
            for (int s2i = 0; s2i < 32; ++s2i) dsum += s_p[s2i][t];
            s_dinv[t] = 1.f / fmaxf(dsum, 1e-12f);
        }
        __syncthreads();

#pragma unroll
        for (int jj = 0; jj < J; ++jj)
            acc = fmaf(e[jj], s_dinv[jj], acc);
    }
    partial[((size_t)b * 8 + chunk) * KCB + t] = acc;
}

// ---------------------------------------------------------------------------
// Tail: pooled = sum(partial)/1024; z = relu(pooled @ l1w^T + b); out = z @ l2w^T + b
// ---------------------------------------------------------------------------
__global__ __launch_bounds__(512) void tail_kernel(
    const float* __restrict__ partial,
    const float* __restrict__ l1w, const float* __restrict__ l1b,
    const float* __restrict__ l2w, const float* __restrict__ l2b,
    float* __restrict__ out)
{
    const int b = blockIdx.x;
    const int t = threadIdx.x;
    __shared__ float s_pool[KCB];
    __shared__ float s_z[20];

    float s = 0.f;
#pragma unroll
    for (int c = 0; c < 8; ++c)
        s += partial[((size_t)b * 8 + c) * KCB + t];
    s_pool[t] = s * (1.0f / 1024.0f);
    __syncthreads();

    if (t < 320) {
        const int row = t >> 4;
        const int l   = t & 15;
        float a = 0.f;
        const float* wr = l1w + (size_t)row * KCB;
#pragma unroll
        for (int m = 0; m < 32; ++m)
            a = fmaf(s_pool[l + 16 * m], wr[l + 16 * m], a);
#pragma unroll
        for (int off = 1; off < 16; off <<= 1)
            a += __shfl_xor(a, off);
        if (l == 0) s_z[row] = fmaxf(a + l1b[row], 0.f);
    }
    __syncthreads();

    if (t < 10) {
        float s2 = l2b[t];
#pragma unroll
        for (int j = 0; j < 20; ++j) s2 = fmaf(s_z[j], l2w[t * 20 + j], s2);
        out[b * 10 + t] = s2;
    }
}

// ---------------------------------------------------------------------------
extern "C" void kernel_launch(void* const* d_in, const int* in_sizes, int n_in,
                              void* d_out, int out_size, void* d_ws, size_t ws_size,
                              hipStream_t stream)
{
    const float* x        = (const float*)d_in[0];
    const float* w1       = (const float*)d_in[1];
    const float* b1       = (const float*)d_in[2];
    const float* w2       = (const float*)d_in[3];
    const float* b2       = (const float*)d_in[4];
    const float* w3       = (const float*)d_in[5];
    const float* b3       = (const float*)d_in[6];
    const float* w4       = (const float*)d_in[7];
    const float* b4       = (const float*)d_in[8];
    const float* codebook = (const float*)d_in[9];
    const float* sigma    = (const float*)d_in[10];
    const float* l1w      = (const float*)d_in[11];
    const float* l1b      = (const float*)d_in[12];
    const float* l2w      = (const float*)d_in[13];
    const float* l2b      = (const float*)d_in[14];
    float* out = (float*)d_out;

    float* ws = (float*)d_ws;
    const size_t N_WT1 = 432;
    const size_t N_WT2 = 2304;
    const size_t N_WT3 = 3456;
    const size_t N_WT4 = 3456;
    const size_t N_C1 = (size_t)BATCH * 16 * 64 * 64;
    const size_t N_P  = (size_t)BATCH * 16 * 32 * 32;
    const size_t N_C3 = (size_t)BATCH * 24 * 32 * 32;
    const size_t N_FT = (size_t)BATCH * 1024 * 16;
    const size_t N_F2 = (size_t)4 * BATCH * 1024;
    const size_t N_PART = (size_t)BATCH * 8 * KCB;

    float* wt1  = ws;  ws += N_WT1;
    float* wt2  = ws;  ws += N_WT2;
    float* wt3  = ws;  ws += N_WT3;
    float* wt4  = ws;  ws += N_WT4;
    float* c1   = ws;  ws += N_C1;
    float* p    = ws;  ws += N_P;
    float* c3   = ws;  ws += N_C3;
    float* ft   = ws;  ws += N_FT;
    float* f2p  = ws;  ws += N_F2;
    float* part = ws;  ws += N_PART;

    // weight transpose (9648 elements)
    wtrans_kernel<<<38, 256, 0, stream>>>(w1, w2, w3, w4, wt1, wt2, wt3, wt4);
    // conv1: (B,3,64,64) -> (B,16,64,64)
    conv1_row_kernel<<<dim3(16, BATCH), 256, 0, stream>>>(x, wt1, b1, c1);
    // conv2 + maxpool: (B,16,64,64) -> (B,16,32,32)
    conv2_pool_kernel<<<dim3(8, BATCH), 256, 0, stream>>>(c1, wt2, b2, p);
    // conv3: (B,16,32,32) -> (B,24,32,32), 4 groups of 6
    conv_rp32_kernel<16, 6, 24><<<dim3(4, 4, BATCH), 256, 0, stream>>>(p, wt3, b3, c3);
    // conv4 -> transposed features + partial norms, 4 groups of 4
    conv4_ft_kernel<<<dim3(4, 4, BATCH), 256, 0, stream>>>(c3, wt4, b4, ft, f2p);
    // BoF membership + partial pooling
    bof_kernel<<<dim3(8, BATCH), 512, 0, stream>>>(ft, f2p, codebook, sigma, part);
    // pooled mean + MLP head
    tail_kernel<<<BATCH, 512, 0, stream>>>(part, l1w, l1b, l2w, l2b, out);
}

// Round 6
// 116.887 us; speedup vs baseline: 1.7275x; 1.7275x over previous
//
#include <hip/hip_runtime.h>
#include <hip/hip_bf16.h>

#define KCB 512
#define DF  16
#define BATCH 64

__device__ __forceinline__ float bperm(int addr, float v) {
    return __int_as_float(__builtin_amdgcn_ds_bpermute(addr, __float_as_int(v)));
}

// ---------------------------------------------------------------------------
// One-shot weight transpose to [c][ky][kx][o] so conv inner loops read weights
// as block-uniform contiguous s_load blocks.
// ---------------------------------------------------------------------------
__global__ __launch_bounds__(256) void wtrans_kernel(
    const float* __restrict__ w1, const float* __restrict__ w2,
    const float* __restrict__ w3, const float* __restrict__ w4,
    float* __restrict__ wt1, float* __restrict__ wt2,
    float* __restrict__ wt3, float* __restrict__ wt4)
{
    int i = blockIdx.x * 256 + threadIdx.x;
    if (i < 432) {                       // conv1: 3*9*16
        int o = i & 15, rest = i >> 4;
        int kx = rest % 3, ky = (rest / 3) % 3, c = rest / 9;
        wt1[i] = w1[((o * 3 + c) * 3 + ky) * 3 + kx];
        return;
    }
    i -= 432;
    if (i < 2304) {                      // conv2: 16*9*16
        int o = i & 15, rest = i >> 4;
        int kx = rest % 3, ky = (rest / 3) % 3, c = rest / 9;
        wt2[i] = w2[((o * 16 + c) * 3 + ky) * 3 + kx];
        return;
    }
    i -= 2304;
    if (i < 3456) {                      // conv3: 16*9*24
        int o = i % 24, rest = i / 24;
        int kx = rest % 3, ky = (rest / 3) % 3, c = rest / 9;
        wt3[i] = w3[((o * 16 + c) * 3 + ky) * 3 + kx];
        return;
    }
    i -= 3456;
    if (i < 3456) {                      // conv4: 24*9*16
        int o = i & 15, rest = i >> 4;
        int kx = rest % 3, ky = (rest / 3) % 3, c = rest / 9;
        wt4[i] = w4[((o * 24 + c) * 3 + ky) * 3 + kx];
    }
}

// ---------------------------------------------------------------------------
// 64-wide row conv (conv1). One wave per output row, COUT_T outs per wave.
// Neighbors via clamped shifted loads (no bpermute chain).
// Grid (16, NG, B), block 256 = 4 waves.
// ---------------------------------------------------------------------------
template<int CIN, int COUT_T, int COUT_TOTAL>
__global__ __launch_bounds__(256) void conv_row64_kernel(
    const float* __restrict__ in, const float* __restrict__ wt,
    const float* __restrict__ bias, float* __restrict__ out)
{
    const int H = 64, W = 64;
    const int lane = threadIdx.x & 63;
    const int wv = threadIdx.x >> 6;
    const int y = blockIdx.x * 4 + wv;
    const int og = blockIdx.y * COUT_T;
    const int b = blockIdx.z;
    const int x = lane;
    const int xl = max(x - 1, 0);
    const int xr = min(x + 1, W - 1);

    float acc[COUT_T];
#pragma unroll
    for (int o = 0; o < COUT_T; ++o) acc[o] = bias[og + o];

#pragma unroll
    for (int c = 0; c < CIN; ++c) {
        const float* ip = in + ((size_t)(b * CIN + c) * H) * W;
#pragma unroll
        for (int ky = 0; ky < 3; ++ky) {
            int ry = y + ky - 1;
            int ryc = min(max(ry, 0), H - 1);
            const float* rp = ip + ryc * W;
            float tc = rp[x], tl = rp[xl], tr = rp[xr];
            bool ok = (ry == ryc);
            float vc = ok ? tc : 0.f;
            float vl = (ok && x > 0)     ? tl : 0.f;
            float vr = (ok && x < W - 1) ? tr : 0.f;
            const float* wp = wt + ((c * 3 + ky) * 3) * COUT_TOTAL + og;
#pragma unroll
            for (int o = 0; o < COUT_T; ++o) acc[o] = fmaf(vl, wp[o], acc[o]);
#pragma unroll
            for (int o = 0; o < COUT_T; ++o) acc[o] = fmaf(vc, wp[COUT_TOTAL + o], acc[o]);
#pragma unroll
            for (int o = 0; o < COUT_T; ++o) acc[o] = fmaf(vr, wp[2 * COUT_TOTAL + o], acc[o]);
        }
    }
#pragma unroll
    for (int o = 0; o < COUT_T; ++o)
        out[((b * COUT_TOTAL + og + o) * H + y) * W + x] = fmaxf(acc[o], 0.f);
}

// ---------------------------------------------------------------------------
// conv2 (16->16, 64x64) + 2x2 maxpool, COUT split x2 (8 per wave).
// One wave per row pair. Shifted loads; pool via one bpermute at the end.
// Grid (8, 2, B), block 256 = 4 waves.
// ---------------------------------------------------------------------------
__global__ __launch_bounds__(256) void conv2_pool_kernel(
    const float* __restrict__ in, const float* __restrict__ wt,
    const float* __restrict__ bias, float* __restrict__ out)
{
    const int CIN = 16, COUT_T = 8, H = 64, W = 64;
    const int lane = threadIdx.x & 63;
    const int wv = threadIdx.x >> 6;
    const int r = blockIdx.x * 4 + wv;   // row pair 0..31
    const int y0 = r * 2;
    const int og = blockIdx.y * COUT_T;
    const int b = blockIdx.z;
    const int x = lane;
    const int xl = max(x - 1, 0);
    const int xr = min(x + 1, W - 1);
    const int aR = ((lane + 1) & 63) << 2;

    float acc0[COUT_T], acc1[COUT_T];
#pragma unroll
    for (int o = 0; o < COUT_T; ++o) { acc0[o] = bias[og + o]; acc1[o] = bias[og + o]; }

#pragma unroll 4
    for (int c = 0; c < CIN; ++c) {
        const float* ip = in + ((size_t)(b * CIN + c) * H) * W;
        float v[4], vl[4], vr[4];
#pragma unroll
        for (int j = 0; j < 4; ++j) {
            int ry = y0 - 1 + j;
            int ryc = min(max(ry, 0), H - 1);
            const float* rp = ip + ryc * W;
            float tc = rp[x], tl = rp[xl], tr = rp[xr];
            bool ok = (ry == ryc);
            v[j]  = ok ? tc : 0.f;
            vl[j] = (ok && x > 0)     ? tl : 0.f;
            vr[j] = (ok && x < W - 1) ? tr : 0.f;
        }
#pragma unroll
        for (int ky = 0; ky < 3; ++ky) {
            const float* wp = wt + ((c * 3 + ky) * 3) * 16 + og;
#pragma unroll
            for (int kx = 0; kx < 3; ++kx) {
                float a0 = (kx == 0) ? vl[ky]     : (kx == 1) ? v[ky]     : vr[ky];
                float a1 = (kx == 0) ? vl[ky + 1] : (kx == 1) ? v[ky + 1] : vr[ky + 1];
                const float* wq = wp + kx * 16;
#pragma unroll
                for (int o = 0; o < COUT_T; ++o) {
                    float w = wq[o];
                    acc0[o] = fmaf(a0, w, acc0[o]);
                    acc1[o] = fmaf(a1, w, acc1[o]);
                }
            }
        }
    }

    // relu + 2x2 maxpool -> (b, o, r, x/2)
    const int px = x >> 1;
#pragma unroll
    for (int o = 0; o < COUT_T; ++o) {
        float m = fmaxf(fmaxf(acc0[o], acc1[o]), 0.f);
        m = fmaxf(m, bperm(aR, m));
        if ((x & 1) == 0)
            out[((b * 16 + og + o) * 32 + r) * 32 + px] = m;
    }
}

// ---------------------------------------------------------------------------
// 32x32 row-pair conv (conv3). Lane = h*32+x (two rows per wave).
// Shifted loads. Grid (4, NG, B), block 256 = 4 waves.
// ---------------------------------------------------------------------------
template<int CIN, int COUT_T, int COUT_TOTAL>
__global__ __launch_bounds__(256) void conv_rp32_kernel(
    const float* __restrict__ in, const float* __restrict__ wt,
    const float* __restrict__ bias, float* __restrict__ out)
{
    const int H = 32, W = 32;
    const int lane = threadIdx.x & 63;
    const int wv = threadIdx.x >> 6;
    const int p = blockIdx.x * 4 + wv;    // row-pair 0..15
    const int og = blockIdx.y * COUT_T;
    const int b = blockIdx.z;
    const int h = lane >> 5;
    const int x = lane & 31;
    const int y = p * 2 + h;
    const int xl = max(x - 1, 0);
    const int xr = min(x + 1, W - 1);

    float acc[COUT_T];
#pragma unroll
    for (int o = 0; o < COUT_T; ++o) acc[o] = bias[og + o];

#pragma unroll 4
    for (int c = 0; c < CIN; ++c) {
        const float* ip = in + ((size_t)(b * CIN + c) * H) * W;
        float v[3], vl[3], vr[3];
#pragma unroll
        for (int d = 0; d < 3; ++d) {
            int ry = y + d - 1;
            int ryc = min(max(ry, 0), H - 1);
            const float* rp = ip + ryc * W;
            float tc = rp[x], tl = rp[xl], tr = rp[xr];
            bool ok = (ry == ryc);
            v[d]  = ok ? tc : 0.f;
            vl[d] = (ok && x > 0)     ? tl : 0.f;
            vr[d] = (ok && x < W - 1) ? tr : 0.f;
        }
#pragma unroll
        for (int ky = 0; ky < 3; ++ky) {
#pragma unroll
            for (int kx = 0; kx < 3; ++kx) {
                float a = (kx == 0) ? vl[ky] : (kx == 1) ? v[ky] : vr[ky];
                const float* wq = wt + ((c * 3 + ky) * 3 + kx) * COUT_TOTAL + og;
#pragma unroll
                for (int o = 0; o < COUT_T; ++o)
                    acc[o] = fmaf(a, wq[o], acc[o]);
            }
        }
    }
#pragma unroll
    for (int o = 0; o < COUT_T; ++o)
        out[((b * COUT_TOTAL + og + o) * H + y) * W + x] = fmaxf(acc[o], 0.f);
}

// ---------------------------------------------------------------------------
// conv4 (24->16, 32x32), COUT split 4x4, shifted loads. Writes float4 slice
// of transposed features ft (B,1024,16) + partial sq-norm f2p.
// Grid (4, 4, B), block 256.
// ---------------------------------------------------------------------------
__global__ __launch_bounds__(256) void conv4_ft_kernel(
    const float* __restrict__ in, const float* __restrict__ wt,
    const float* __restrict__ bias, float* __restrict__ ft,
    float* __restrict__ f2p)
{
    const int CIN = 24, COUT_T = 4, H = 32, W = 32;
    const int lane = threadIdx.x & 63;
    const int wv = threadIdx.x >> 6;
    const int p = blockIdx.x * 4 + wv;
    const int g = blockIdx.y;
    const int og = g * COUT_T;
    const int b = blockIdx.z;
    const int h = lane >> 5;
    const int x = lane & 31;
    const int y = p * 2 + h;
    const int xl = max(x - 1, 0);
    const int xr = min(x + 1, W - 1);

    float acc[COUT_T];
#pragma unroll
    for (int o = 0; o < COUT_T; ++o) acc[o] = bias[og + o];

#pragma unroll 4
    for (int c = 0; c < CIN; ++c) {
        const float* ip = in + ((size_t)(b * CIN + c) * H) * W;
        float v[3], vl[3], vr[3];
#pragma unroll
        for (int d = 0; d < 3; ++d) {
            int ry = y + d - 1;
            int ryc = min(max(ry, 0), H - 1);
            const float* rp = ip + ryc * W;
            float tc = rp[x], tl = rp[xl], tr = rp[xr];
            bool ok = (ry == ryc);
            v[d]  = ok ? tc : 0.f;
            vl[d] = (ok && x > 0)     ? tl : 0.f;
            vr[d] = (ok && x < W - 1) ? tr : 0.f;
        }
#pragma unroll
        for (int ky = 0; ky < 3; ++ky) {
#pragma unroll
            for (int kx = 0; kx < 3; ++kx) {
                float a = (kx == 0) ? vl[ky] : (kx == 1) ? v[ky] : vr[ky];
                const float* wq = wt + ((c * 3 + ky) * 3 + kx) * 16 + og;
#pragma unroll
                for (int o = 0; o < COUT_T; ++o)
                    acc[o] = fmaf(a, wq[o], acc[o]);
            }
        }
    }

    const size_t pix = (size_t)b * 1024 + y * W + x;
    float v0 = fmaxf(acc[0], 0.f), v1 = fmaxf(acc[1], 0.f);
    float v2 = fmaxf(acc[2], 0.f), v3 = fmaxf(acc[3], 0.f);
    *(float4*)(ft + pix * 16 + og) = make_float4(v0, v1, v2, v3);
    float s2 = v0 * v0;
    s2 = fmaf(v1, v1, s2);
    s2 = fmaf(v2, v2, s2);
    s2 = fmaf(v3, v3, s2);
    f2p[(size_t)g * (BATCH * 1024) + pix] = s2;
}

// ---------------------------------------------------------------------------
// BoF: dist = f2 + c2 - 2 f.c. 64-pixel chunks -> 1024 blocks (4/CU).
// Denominator per 16-px batch: 16-row column sums + shfl_xor(16,32) wave
// combine + 8-read tail. Grid (16, B), block 512 (thread = codebook entry).
// partial: (B,16,512).
// ---------------------------------------------------------------------------
__global__ __launch_bounds__(512) void bof_kernel(
    const float* __restrict__ ft, const float* __restrict__ f2p,
    const float* __restrict__ codebook, const float* __restrict__ sigma,
    float* __restrict__ partial)
{
    const int J = 16;
    const int PIX = 64;
    const int b = blockIdx.y;
    const int chunk = blockIdx.x;       // 0..15
    const int t = threadIdx.x;
    const int lane = t & 63;
    const int w = t >> 6;

    __shared__ float s_e[KCB][J + 1];
    __shared__ float s_q[8][16];
    __shared__ float s_dinv[J];
    __shared__ float s_tmp[4][PIX];
    __shared__ float s_f2[PIX];

    const size_t base = (size_t)b * 1024 + chunk * PIX;
    if (t < 256) {
        const int g = t >> 6, j = t & 63;
        s_tmp[g][j] = f2p[(size_t)g * (BATCH * 1024) + base + j];
    }

    float cb[DF];
    {
        const float4* cq = (const float4*)(codebook + (size_t)t * DF);
        float4 a0 = cq[0], a1 = cq[1], a2 = cq[2], a3 = cq[3];
        cb[0]=a0.x; cb[1]=a0.y; cb[2]=a0.z; cb[3]=a0.w;
        cb[4]=a1.x; cb[5]=a1.y; cb[6]=a1.z; cb[7]=a1.w;
        cb[8]=a2.x; cb[9]=a2.y; cb[10]=a2.z; cb[11]=a2.w;
        cb[12]=a3.x; cb[13]=a3.y; cb[14]=a3.z; cb[15]=a3.w;
    }
    float c2 = 0.f;
#pragma unroll
    for (int d = 0; d < DF; ++d) c2 = fmaf(cb[d], cb[d], c2);
    const float sg = sigma[t];

    __syncthreads();
    if (t < PIX) s_f2[t] = (s_tmp[0][t] + s_tmp[1][t]) + (s_tmp[2][t] + s_tmp[3][t]);
    __syncthreads();

    float acc = 0.f;

    for (int jb = 0; jb < PIX / J; ++jb) {   // 4 batches
        const int j0 = jb * J;
        float e[J];
#pragma unroll
        for (int jj = 0; jj < J; ++jj) {
            const float* fp = ft + (base + j0 + jj) * DF;  // uniform -> s_load
            float dot = 0.f;
#pragma unroll
            for (int d = 0; d < DF; ++d) dot = fmaf(fp[d], cb[d], dot);
            float f2c = s_f2[j0 + jj] + c2;                // LDS broadcast
            float dist = fmaf(-2.f, dot, f2c);
            e[jj] = __expf(-dist * sg);
            s_e[t][jj] = e[jj];
        }
        __syncthreads();

        // column partials: each thread sums 16 rows of its column (c = t&15),
        // then combine the wave's 4 segments via shfl_xor(16), shfl_xor(32).
        {
            const int c   = t & 15;
            const int seg = t >> 4;          // 0..31
            float ps = 0.f;
#pragma unroll
            for (int r = 0; r < 16; ++r) ps += s_e[seg * 16 + r][c];
            ps += __shfl_xor(ps, 16);
            ps += __shfl_xor(ps, 32);        // now: sum of rows 64w..64w+63, col c
            if (lane < 16) s_q[w][lane] = ps;
        }
        __syncthreads();

        if (t < J) {
            float dsum = 0.f;
#pragma unroll
            for (int i = 0; i < 8; ++i) dsum += s_q[i][t];
            s_dinv[t] = 1.f / fmaxf(dsum, 1e-12f);
        }
        __syncthreads();

#pragma unroll
        for (int jj = 0; jj < J; ++jj)
            acc = fmaf(e[jj], s_dinv[jj], acc);
    }
    partial[((size_t)b * 16 + chunk) * KCB + t] = acc;
}

// ---------------------------------------------------------------------------
// Tail: pooled = sum(partial)/1024; z = relu(pooled @ l1w^T + b); out = z @ l2w^T + b
// ---------------------------------------------------------------------------
__global__ __launch_bounds__(512) void tail_kernel(
    const float* __restrict__ partial,
    const float* __restrict__ l1w, const float* __restrict__ l1b,
    const float* __restrict__ l2w, const float* __restrict__ l2b,
    float* __restrict__ out)
{
    const int b = blockIdx.x;
    const int t = threadIdx.x;
    __shared__ float s_pool[KCB];
    __shared__ float s_z[20];

    float s = 0.f;
#pragma unroll
    for (int c = 0; c < 16; ++c)
        s += partial[((size_t)b * 16 + c) * KCB + t];
    s_pool[t] = s * (1.0f / 1024.0f);
    __syncthreads();

    if (t < 320) {
        const int row = t >> 4;
        const int l   = t & 15;
        float a = 0.f;
        const float* wr = l1w + (size_t)row * KCB;
#pragma unroll
        for (int m = 0; m < 32; ++m)
            a = fmaf(s_pool[l + 16 * m], wr[l + 16 * m], a);
#pragma unroll
        for (int off = 1; off < 16; off <<= 1)
            a += __shfl_xor(a, off);
        if (l == 0) s_z[row] = fmaxf(a + l1b[row], 0.f);
    }
    __syncthreads();

    if (t < 10) {
        float s2 = l2b[t];
#pragma unroll
        for (int j = 0; j < 20; ++j) s2 = fmaf(s_z[j], l2w[t * 20 + j], s2);
        out[b * 10 + t] = s2;
    }
}

// ---------------------------------------------------------------------------
extern "C" void kernel_launch(void* const* d_in, const int* in_sizes, int n_in,
                              void* d_out, int out_size, void* d_ws, size_t ws_size,
                              hipStream_t stream)
{
    const float* x        = (const float*)d_in[0];
    const float* w1       = (const float*)d_in[1];
    const float* b1       = (const float*)d_in[2];
    const float* w2       = (const float*)d_in[3];
    const float* b2       = (const float*)d_in[4];
    const float* w3       = (const float*)d_in[5];
    const float* b3       = (const float*)d_in[6];
    const float* w4       = (const float*)d_in[7];
    const float* b4       = (const float*)d_in[8];
    const float* codebook = (const float*)d_in[9];
    const float* sigma    = (const float*)d_in[10];
    const float* l1w      = (const float*)d_in[11];
    const float* l1b      = (const float*)d_in[12];
    const float* l2w      = (const float*)d_in[13];
    const float* l2b      = (const float*)d_in[14];
    float* out = (float*)d_out;

    float* ws = (float*)d_ws;
    const size_t N_WT1 = 432;
    const size_t N_WT2 = 2304;
    const size_t N_WT3 = 3456;
    const size_t N_WT4 = 3456;
    const size_t N_C1 = (size_t)BATCH * 16 * 64 * 64;
    const size_t N_P  = (size_t)BATCH * 16 * 32 * 32;
    const size_t N_C3 = (size_t)BATCH * 24 * 32 * 32;
    const size_t N_FT = (size_t)BATCH * 1024 * 16;
    const size_t N_F2 = (size_t)4 * BATCH * 1024;
    const size_t N_PART = (size_t)BATCH * 16 * KCB;

    float* wt1  = ws;  ws += N_WT1;
    float* wt2  = ws;  ws += N_WT2;
    float* wt3  = ws;  ws += N_WT3;
    float* wt4  = ws;  ws += N_WT4;
    float* c1   = ws;  ws += N_C1;
    float* p    = ws;  ws += N_P;
    float* c3   = ws;  ws += N_C3;
    float* ft   = ws;  ws += N_FT;
    float* f2p  = ws;  ws += N_F2;
    float* part = ws;  ws += N_PART;

    // weight transpose
    wtrans_kernel<<<38, 256, 0, stream>>>(w1, w2, w3, w4, wt1, wt2, wt3, wt4);
    // conv1: (B,3,64,64) -> (B,16,64,64), 2 groups of 8
    conv_row64_kernel<3, 8, 16><<<dim3(16, 2, BATCH), 256, 0, stream>>>(x, wt1, b1, c1);
    // conv2 + maxpool: (B,16,64,64) -> (B,16,32,32), 2 groups of 8
    conv2_pool_kernel<<<dim3(8, 2, BATCH), 256, 0, stream>>>(c1, wt2, b2, p);
    // conv3: (B,16,32,32) -> (B,24,32,32), 8 groups of 3
    conv_rp32_kernel<16, 3, 24><<<dim3(4, 8, BATCH), 256, 0, stream>>>(p, wt3, b3, c3);
    // conv4 -> transposed features + partial norms, 4 groups of 4
    conv4_ft_kernel<<<dim3(4, 4, BATCH), 256, 0, stream>>>(c3, wt4, b4, ft, f2p);
    // BoF membership + partial pooling (64-px chunks)
    bof_kernel<<<dim3(16, BATCH), 512, 0, stream>>>(ft, f2p, codebook, sigma, part);
    // pooled mean + MLP head
    tail_kernel<<<BATCH, 512, 0, stream>>>(part, l1w, l1b, l2w, l2b, out);
}